// Round 3
// baseline (164.938 us; speedup 1.0000x reference)
//
#include <hip/hip_runtime.h>
#include <hip/hip_bf16.h>

// PE table: out[pos, 2i]   = sin(pos / 10000^(2i/1024))
//           out[pos, 2i+1] = cos(pos / 10000^(2i/1024))
// Output f32 [seq_len, 1024]. Input X is only used for its shape -> never read.
//
// Native-trig path: v_sin/v_cos take REVOLUTIONS (D = sin(S0*2pi)), so fold
// 1/(2*pi) into the exp2 exponent:
//   rev = pos * 2^(-i*K - log2(2*pi)),  K = 2*log2(10000)/D_MODEL.
// fract() before sin/cos is mandatory: rev reaches ~1304, outside v_sin's
// accurate range; after fract, rev in [0,1).
//
// Structure: one block of 256 threads covers a full 1024-float row per
// iteration (thread t -> float4 column t, 4 KB contiguous store). Each block
// grid-strides over ROWS_PER_BLOCK rows; the column-dependent exp2 factors
// are computed ONCE per thread and reused across rows.

#define D_MODEL 1024

__global__ __launch_bounds__(256) void PositionalEncoding_31559419691757_kernel(
    float4* __restrict__ out, int rows, int rows_per_block) {
    const float K = 0.025952563241307522f;  // 2*log2(10000)/D_MODEL
    const float C = 2.6514961294723187f;    // log2(2*pi)

    int c4 = threadIdx.x;                    // float4-column 0..255
    float i0 = (float)(2 * c4);              // pair index of .x/.y
    float i1 = i0 + 1.0f;                    // pair index of .z/.w

    // Column-only factors: computed once, reused for every row this block does.
    float e0 = __builtin_amdgcn_exp2f(-(i0 * K) - C);   // v_exp_f32
    float e1 = __builtin_amdgcn_exp2f(-(i1 * K) - C);

    int row0 = blockIdx.x * rows_per_block;
    int row1 = min(row0 + rows_per_block, rows);
    for (int row = row0; row < row1; ++row) {
        float fpos = (float)row;
        float r0 = __builtin_amdgcn_fractf(fpos * e0);  // v_fract_f32
        float r1 = __builtin_amdgcn_fractf(fpos * e1);
        float4 v;
        v.x = __builtin_amdgcn_sinf(r0);   // v_sin_f32: sin(2*pi*r0)
        v.y = __builtin_amdgcn_cosf(r0);   // v_cos_f32
        v.z = __builtin_amdgcn_sinf(r1);
        v.w = __builtin_amdgcn_cosf(r1);
        out[row * (D_MODEL / 4) + c4] = v;
    }
}

extern "C" void kernel_launch(void* const* d_in, const int* in_sizes, int n_in,
                              void* d_out, int out_size, void* d_ws, size_t ws_size,
                              hipStream_t stream) {
    (void)d_in; (void)in_sizes; (void)n_in; (void)d_ws; (void)ws_size;
    int rows = out_size / D_MODEL;           // seq_len (8192 for this problem)
    const int target_blocks = 2048;          // G11: ~2048 blocks, grid-stride rest
    int rows_per_block = (rows + target_blocks - 1) / target_blocks;
    int blocks = (rows + rows_per_block - 1) / rows_per_block;
    PositionalEncoding_31559419691757_kernel<<<blocks, 256, 0, stream>>>(
        (float4*)d_out, rows, rows_per_block);
}